// Round 2
// baseline (3367.665 us; speedup 1.0000x reference)
//
#include <hip/hip_runtime.h>

#define N_NODES 50000
#define IN_CH 128
#define HID 128
#define OUT_CH 40
#define N_LAYERS 3
#define N_EDGES 600000

// ---------------------------------------------------------------------------
// Scatter-add: aggr[dst] += h[src]  (aggr pre-zeroed). 32 threads per edge,
// each thread handles 4 channels via one float4 gather + 4 scalar atomics.
// NOTE: edge_index arrives as int32 (JAX default x64-disabled downcasts).
// ---------------------------------------------------------------------------
__global__ __launch_bounds__(256) void scatter_kernel(
    const float* __restrict__ h, const int* __restrict__ ei,
    float* __restrict__ aggr) {
  long long t = (long long)blockIdx.x * 256 + threadIdx.x;
  int e = (int)(t >> 5);
  int q = (int)(t & 31);
  if (e >= N_EDGES) return;
  int s = ei[e];            // src
  int d = ei[N_EDGES + e];  // dst
  const float4 v = *(const float4*)(h + (size_t)s * 128 + q * 4);
  float* o = aggr + (size_t)d * 128 + q * 4;
  atomicAdd(o + 0, v.x);
  atomicAdd(o + 1, v.y);
  atomicAdd(o + 2, v.z);
  atomicAdd(o + 3, v.w);
}

// ---------------------------------------------------------------------------
// C[M,128] = act(（A (+A2)）[M,128] @ W[128,128] + bias)
// 256 threads, 128x128 tile per block, 8x8 outputs/thread (split 4+4 in both
// dims so LDS reads are <=2-way bank aliased = free). BK=32.
// In-place C == A2 is safe: each block touches only its own 128-row slice and
// all global reads complete (behind __syncthreads) before the epilogue store.
// ---------------------------------------------------------------------------
template <bool ADD, bool RELU>
__global__ __launch_bounds__(256) void gemm128_kernel(
    const float* __restrict__ A, const float* __restrict__ A2,
    const float* __restrict__ W, const float* __restrict__ bias,
    float* __restrict__ C, int M) {
  __shared__ float As[32][132];  // transposed: As[k][m], padded rows (132*4B % 16 == 0)
  __shared__ float Ws[32][132];  // Ws[k][n]
  const int tid = threadIdx.x;
  const int row0 = blockIdx.x * 128;
  const int tx = tid & 15;  // col group: cols {tx*4..+3, 64+tx*4..+3}
  const int ty = tid >> 4;  // row group: rows {ty*4..+3, 64+ty*4..+3}

  float acc[8][8];
#pragma unroll
  for (int r = 0; r < 8; ++r)
#pragma unroll
    for (int c = 0; c < 8; ++c) acc[r][c] = 0.0f;

  for (int k0 = 0; k0 < 128; k0 += 32) {
    // Stage A chunk (128 rows x 32 k), transposed into As[k][m].
#pragma unroll
    for (int j = 0; j < 4; ++j) {
      int i = tid + j * 256;  // 0..1023 float4 slots
      int m = i >> 3;         // 0..127
      int kq = i & 7;         // float4 index within 32-wide k chunk
      int gm = row0 + m;
      float4 v = make_float4(0.f, 0.f, 0.f, 0.f);
      if (gm < M) {
        v = *(const float4*)(A + (size_t)gm * 128 + k0 + kq * 4);
        if (ADD) {
          float4 u = *(const float4*)(A2 + (size_t)gm * 128 + k0 + kq * 4);
          v.x += u.x; v.y += u.y; v.z += u.z; v.w += u.w;
        }
      }
      As[kq * 4 + 0][m] = v.x;
      As[kq * 4 + 1][m] = v.y;
      As[kq * 4 + 2][m] = v.z;
      As[kq * 4 + 3][m] = v.w;
    }
    // Stage W chunk (32 k x 128 n).
#pragma unroll
    for (int j = 0; j < 4; ++j) {
      int i = tid + j * 256;
      int k = i >> 5;
      int nq = i & 31;
      float4 v = *(const float4*)(W + (size_t)(k0 + k) * 128 + nq * 4);
      *(float4*)&Ws[k][nq * 4] = v;
    }
    __syncthreads();

#pragma unroll
    for (int k = 0; k < 32; ++k) {
      float4 a0 = *(const float4*)&As[k][ty * 4];
      float4 a1 = *(const float4*)&As[k][64 + ty * 4];
      float4 w0 = *(const float4*)&Ws[k][tx * 4];
      float4 w1 = *(const float4*)&Ws[k][64 + tx * 4];
      float ar[8] = {a0.x, a0.y, a0.z, a0.w, a1.x, a1.y, a1.z, a1.w};
      float wr[8] = {w0.x, w0.y, w0.z, w0.w, w1.x, w1.y, w1.z, w1.w};
#pragma unroll
      for (int r = 0; r < 8; ++r)
#pragma unroll
        for (int c = 0; c < 8; ++c) acc[r][c] = fmaf(ar[r], wr[c], acc[r][c]);
    }
    __syncthreads();
  }

  // Epilogue: bias (+relu) + store.
  float4 b0 = *(const float4*)&bias[tx * 4];
  float4 b1 = *(const float4*)&bias[64 + tx * 4];
  float br[8] = {b0.x, b0.y, b0.z, b0.w, b1.x, b1.y, b1.z, b1.w};
#pragma unroll
  for (int r = 0; r < 8; ++r) {
    int gm = row0 + ((r < 4) ? (ty * 4 + r) : (64 + ty * 4 + (r - 4)));
    if (gm < M) {
      float4 c0, c1;
      float* cp0 = &c0.x;
      float* cp1 = &c1.x;
#pragma unroll
      for (int c = 0; c < 4; ++c) {
        float v0 = acc[r][c] + br[c];
        float v1 = acc[r][c + 4] + br[c + 4];
        if (RELU) {
          v0 = fmaxf(v0, 0.0f);
          v1 = fmaxf(v1, 0.0f);
        }
        cp0[c] = v0;
        cp1[c] = v1;
      }
      *(float4*)(C + (size_t)gm * 128 + tx * 4) = c0;
      *(float4*)(C + (size_t)gm * 128 + 64 + tx * 4) = c1;
    }
  }
}

// ---------------------------------------------------------------------------
// Final classifier: C[M,40] = A[M,128] @ W[128,40] + bias.
// 256 threads = 32 row-groups(x4 rows) x 8 col-groups(x5 cols).
// ---------------------------------------------------------------------------
__global__ __launch_bounds__(256) void gemm_out_kernel(
    const float* __restrict__ A, const float* __restrict__ W,
    const float* __restrict__ bias, float* __restrict__ C, int M) {
  __shared__ float As[32][132];
  __shared__ float Ws[32][48];
  const int tid = threadIdx.x;
  const int row0 = blockIdx.x * 128;
  const int tx = tid & 7;   // col group: cols tx*5..tx*5+4
  const int ty = tid >> 3;  // row group: rows ty*4..ty*4+3

  float acc[4][5];
#pragma unroll
  for (int r = 0; r < 4; ++r)
#pragma unroll
    for (int c = 0; c < 5; ++c) acc[r][c] = 0.0f;

  for (int k0 = 0; k0 < 128; k0 += 32) {
#pragma unroll
    for (int j = 0; j < 4; ++j) {
      int i = tid + j * 256;
      int m = i >> 3;
      int kq = i & 7;
      int gm = row0 + m;
      float4 v = make_float4(0.f, 0.f, 0.f, 0.f);
      if (gm < M) v = *(const float4*)(A + (size_t)gm * 128 + k0 + kq * 4);
      As[kq * 4 + 0][m] = v.x;
      As[kq * 4 + 1][m] = v.y;
      As[kq * 4 + 2][m] = v.z;
      As[kq * 4 + 3][m] = v.w;
    }
    for (int i = tid; i < 32 * 40; i += 256) {
      int k = i / 40;
      int n = i % 40;
      Ws[k][n] = W[(size_t)(k0 + k) * 40 + n];
    }
    __syncthreads();

#pragma unroll
    for (int k = 0; k < 32; ++k) {
      float4 a = *(const float4*)&As[k][ty * 4];
      float ar[4] = {a.x, a.y, a.z, a.w};
      float wr[5];
#pragma unroll
      for (int c = 0; c < 5; ++c) wr[c] = Ws[k][tx * 5 + c];
#pragma unroll
      for (int r = 0; r < 4; ++r)
#pragma unroll
        for (int c = 0; c < 5; ++c) acc[r][c] = fmaf(ar[r], wr[c], acc[r][c]);
    }
    __syncthreads();
  }

#pragma unroll
  for (int r = 0; r < 4; ++r) {
    int gm = row0 + ty * 4 + r;
    if (gm < M) {
#pragma unroll
      for (int c = 0; c < 5; ++c) {
        C[(size_t)gm * OUT_CH + tx * 5 + c] = acc[r][c] + bias[tx * 5 + c];
      }
    }
  }
}

// ---------------------------------------------------------------------------
extern "C" void kernel_launch(void* const* d_in, const int* in_sizes, int n_in,
                              void* d_out, int out_size, void* d_ws,
                              size_t ws_size, hipStream_t stream) {
  const float* x = (const float*)d_in[0];
  // d_in[1] = edge_attr — unused by the reference.
  const int* ei = (const int*)d_in[2];  // int32 [2, E] (harness passes ints as int32)
  const float* W1 = (const float*)d_in[3];
  const float* b1 = (const float*)d_in[4];
  const float* W2 = (const float*)d_in[5];
  const float* b2 = (const float*)d_in[6];
  const float* Wc = (const float*)d_in[7];
  const float* bc = (const float*)d_in[8];
  float* out = (float*)d_out;

  float* bufA = (float*)d_ws;
  float* bufB = bufA + (size_t)N_NODES * 128;
  const size_t fbytes = (size_t)N_NODES * 128 * sizeof(float);

  const dim3 blk(256);
  const int gemm_grid = (N_NODES + 127) / 128;        // 391
  const int scat_grid = (N_EDGES * 32 + 255) / 256;   // 75000

  const float* h = x;
  float* pA = bufA;
  float* pB = bufB;
  for (int l = 0; l < N_LAYERS; ++l) {
    // aggr (pA) = 0; aggr += h[src] at dst
    hipMemsetAsync(pA, 0, fbytes, stream);
    scatter_kernel<<<scat_grid, blk, 0, stream>>>(h, ei, pA);
    // pB = relu((h + aggr) @ W1[l] + b1[l])   (A2-add fused into staging)
    gemm128_kernel<true, true><<<gemm_grid, blk, 0, stream>>>(
        pA, h, W1 + (size_t)l * 128 * 128, b1 + (size_t)l * 128, pB, N_NODES);
    // pA = relu(pB @ W2[l] + b2[l])
    gemm128_kernel<false, true><<<gemm_grid, blk, 0, stream>>>(
        pB, nullptr, W2 + (size_t)l * 128 * 128, b2 + (size_t)l * 128, pA,
        N_NODES);
    h = pA;
    float* t = pA;
    pA = pB;
    pB = t;
  }
  // out = h @ Wc + bc
  gemm_out_kernel<<<gemm_grid, blk, 0, stream>>>(h, Wc, bc, out, N_NODES);
}

// Round 3
// 645.743 us; speedup vs baseline: 5.2152x; 5.2152x over previous
//
#include <hip/hip_runtime.h>

#define N_NODES 50000
#define IN_CH 128
#define HID 128
#define OUT_CH 40
#define N_LAYERS 3
#define N_EDGES 600000

// ============================ CSR construction =============================
// deg histogram over dst. deg[] pre-zeroed by memset.
__global__ __launch_bounds__(256) void count_kernel(
    const int* __restrict__ ei, int* __restrict__ deg) {
  int e = blockIdx.x * 256 + threadIdx.x;
  if (e >= N_EDGES) return;
  atomicAdd(&deg[ei[N_EDGES + e]], 1);
}

// Single-block exclusive scan of deg[50000] -> offsets[50001], copy to cursors.
__global__ __launch_bounds__(1024) void scan_kernel(
    const int* __restrict__ deg, int* __restrict__ offsets,
    int* __restrict__ cursors) {
  __shared__ int sums[1024];
  const int t = threadIdx.x;
  const int STRIP = (N_NODES + 1023) / 1024;  // 49
  const int base = t * STRIP;
  int local = 0;
  for (int i = 0; i < STRIP; ++i) {
    int idx = base + i;
    if (idx < N_NODES) local += deg[idx];
  }
  sums[t] = local;
  __syncthreads();
  // Hillis-Steele inclusive scan over 1024 partials.
  for (int off = 1; off < 1024; off <<= 1) {
    int v = 0;
    if (t >= off) v = sums[t - off];
    __syncthreads();
    if (t >= off) sums[t] += v;
    __syncthreads();
  }
  int run = (t == 0) ? 0 : sums[t - 1];
  for (int i = 0; i < STRIP; ++i) {
    int idx = base + i;
    if (idx < N_NODES) {
      offsets[idx] = run;
      cursors[idx] = run;
      run += deg[idx];
    }
  }
  if (t == 1023) offsets[N_NODES] = sums[1023];
}

// Fill col[] via atomic cursors (order within a node irrelevant for sum).
__global__ __launch_bounds__(256) void fill_kernel(
    const int* __restrict__ ei, int* __restrict__ cursors,
    int* __restrict__ col) {
  int e = blockIdx.x * 256 + threadIdx.x;
  if (e >= N_EDGES) return;
  int s = ei[e];
  int d = ei[N_EDGES + e];
  int pos = atomicAdd(&cursors[d], 1);
  col[pos] = s;
}

// ======================= Aggregation: z = h[n] + sum ========================
// 32 threads per node (8 nodes / 256-thread block); each thread owns 4
// channels (float4). Per neighbor: one coalesced 512B row read across the
// half-wave. No atomics, single write per output element.
__global__ __launch_bounds__(256) void aggregate_kernel(
    const float* __restrict__ h, const int* __restrict__ offsets,
    const int* __restrict__ col, float* __restrict__ z) {
  int t = blockIdx.x * 256 + threadIdx.x;
  int n = t >> 5;
  int q = t & 31;
  if (n >= N_NODES) return;
  float4 acc = *(const float4*)(h + (size_t)n * 128 + q * 4);  // self (eps=0)
  int beg = offsets[n];
  int end = offsets[n + 1];
  for (int i = beg; i < end; ++i) {
    int s = col[i];
    const float4 v = *(const float4*)(h + (size_t)s * 128 + q * 4);
    acc.x += v.x; acc.y += v.y; acc.z += v.z; acc.w += v.w;
  }
  *(float4*)(z + (size_t)n * 128 + q * 4) = acc;
}

// ---------------------------------------------------------------------------
// C[M,128] = act(A[M,128] @ W[128,128] + bias)
// 256 threads, 128x128 tile per block, 8x8 outputs/thread (split 4+4 in both
// dims so LDS reads are <=2-way bank aliased = free). BK=32.
// ---------------------------------------------------------------------------
template <bool RELU>
__global__ __launch_bounds__(256) void gemm128_kernel(
    const float* __restrict__ A, const float* __restrict__ W,
    const float* __restrict__ bias, float* __restrict__ C, int M) {
  __shared__ float As[32][132];  // transposed: As[k][m]
  __shared__ float Ws[32][132];  // Ws[k][n]
  const int tid = threadIdx.x;
  const int row0 = blockIdx.x * 128;
  const int tx = tid & 15;  // col group: cols {tx*4..+3, 64+tx*4..+3}
  const int ty = tid >> 4;  // row group: rows {ty*4..+3, 64+ty*4..+3}

  float acc[8][8];
#pragma unroll
  for (int r = 0; r < 8; ++r)
#pragma unroll
    for (int c = 0; c < 8; ++c) acc[r][c] = 0.0f;

  for (int k0 = 0; k0 < 128; k0 += 32) {
#pragma unroll
    for (int j = 0; j < 4; ++j) {
      int i = tid + j * 256;  // 0..1023 float4 slots
      int m = i >> 3;
      int kq = i & 7;
      int gm = row0 + m;
      float4 v = make_float4(0.f, 0.f, 0.f, 0.f);
      if (gm < M) v = *(const float4*)(A + (size_t)gm * 128 + k0 + kq * 4);
      As[kq * 4 + 0][m] = v.x;
      As[kq * 4 + 1][m] = v.y;
      As[kq * 4 + 2][m] = v.z;
      As[kq * 4 + 3][m] = v.w;
    }
#pragma unroll
    for (int j = 0; j < 4; ++j) {
      int i = tid + j * 256;
      int k = i >> 5;
      int nq = i & 31;
      float4 v = *(const float4*)(W + (size_t)(k0 + k) * 128 + nq * 4);
      *(float4*)&Ws[k][nq * 4] = v;
    }
    __syncthreads();

#pragma unroll
    for (int k = 0; k < 32; ++k) {
      float4 a0 = *(const float4*)&As[k][ty * 4];
      float4 a1 = *(const float4*)&As[k][64 + ty * 4];
      float4 w0 = *(const float4*)&Ws[k][tx * 4];
      float4 w1 = *(const float4*)&Ws[k][64 + tx * 4];
      float ar[8] = {a0.x, a0.y, a0.z, a0.w, a1.x, a1.y, a1.z, a1.w};
      float wr[8] = {w0.x, w0.y, w0.z, w0.w, w1.x, w1.y, w1.z, w1.w};
#pragma unroll
      for (int r = 0; r < 8; ++r)
#pragma unroll
        for (int c = 0; c < 8; ++c) acc[r][c] = fmaf(ar[r], wr[c], acc[r][c]);
    }
    __syncthreads();
  }

  float4 b0 = *(const float4*)&bias[tx * 4];
  float4 b1 = *(const float4*)&bias[64 + tx * 4];
  float br[8] = {b0.x, b0.y, b0.z, b0.w, b1.x, b1.y, b1.z, b1.w};
#pragma unroll
  for (int r = 0; r < 8; ++r) {
    int gm = row0 + ((r < 4) ? (ty * 4 + r) : (64 + ty * 4 + (r - 4)));
    if (gm < M) {
      float4 c0, c1;
      float* cp0 = &c0.x;
      float* cp1 = &c1.x;
#pragma unroll
      for (int c = 0; c < 4; ++c) {
        float v0 = acc[r][c] + br[c];
        float v1 = acc[r][c + 4] + br[c + 4];
        if (RELU) {
          v0 = fmaxf(v0, 0.0f);
          v1 = fmaxf(v1, 0.0f);
        }
        cp0[c] = v0;
        cp1[c] = v1;
      }
      *(float4*)(C + (size_t)gm * 128 + tx * 4) = c0;
      *(float4*)(C + (size_t)gm * 128 + 64 + tx * 4) = c1;
    }
  }
}

// ---------------------------------------------------------------------------
// Final classifier: C[M,40] = A[M,128] @ W[128,40] + bias.
// ---------------------------------------------------------------------------
__global__ __launch_bounds__(256) void gemm_out_kernel(
    const float* __restrict__ A, const float* __restrict__ W,
    const float* __restrict__ bias, float* __restrict__ C, int M) {
  __shared__ float As[32][132];
  __shared__ float Ws[32][48];
  const int tid = threadIdx.x;
  const int row0 = blockIdx.x * 128;
  const int tx = tid & 7;   // cols tx*5..tx*5+4
  const int ty = tid >> 3;  // rows ty*4..ty*4+3

  float acc[4][5];
#pragma unroll
  for (int r = 0; r < 4; ++r)
#pragma unroll
    for (int c = 0; c < 5; ++c) acc[r][c] = 0.0f;

  for (int k0 = 0; k0 < 128; k0 += 32) {
#pragma unroll
    for (int j = 0; j < 4; ++j) {
      int i = tid + j * 256;
      int m = i >> 3;
      int kq = i & 7;
      int gm = row0 + m;
      float4 v = make_float4(0.f, 0.f, 0.f, 0.f);
      if (gm < M) v = *(const float4*)(A + (size_t)gm * 128 + k0 + kq * 4);
      As[kq * 4 + 0][m] = v.x;
      As[kq * 4 + 1][m] = v.y;
      As[kq * 4 + 2][m] = v.z;
      As[kq * 4 + 3][m] = v.w;
    }
    for (int i = tid; i < 32 * 40; i += 256) {
      int k = i / 40;
      int n = i % 40;
      Ws[k][n] = W[(size_t)(k0 + k) * 40 + n];
    }
    __syncthreads();

#pragma unroll
    for (int k = 0; k < 32; ++k) {
      float4 a = *(const float4*)&As[k][ty * 4];
      float ar[4] = {a.x, a.y, a.z, a.w};
      float wr[5];
#pragma unroll
      for (int c = 0; c < 5; ++c) wr[c] = Ws[k][tx * 5 + c];
#pragma unroll
      for (int r = 0; r < 4; ++r)
#pragma unroll
        for (int c = 0; c < 5; ++c) acc[r][c] = fmaf(ar[r], wr[c], acc[r][c]);
    }
    __syncthreads();
  }

#pragma unroll
  for (int r = 0; r < 4; ++r) {
    int gm = row0 + ty * 4 + r;
    if (gm < M) {
#pragma unroll
      for (int c = 0; c < 5; ++c) {
        C[(size_t)gm * OUT_CH + tx * 5 + c] = acc[r][c] + bias[tx * 5 + c];
      }
    }
  }
}

// ---------------------------------------------------------------------------
extern "C" void kernel_launch(void* const* d_in, const int* in_sizes, int n_in,
                              void* d_out, int out_size, void* d_ws,
                              size_t ws_size, hipStream_t stream) {
  const float* x = (const float*)d_in[0];
  // d_in[1] = edge_attr — unused by the reference.
  const int* ei = (const int*)d_in[2];  // int32 [2, E]
  const float* W1 = (const float*)d_in[3];
  const float* b1 = (const float*)d_in[4];
  const float* W2 = (const float*)d_in[5];
  const float* b2 = (const float*)d_in[6];
  const float* Wc = (const float*)d_in[7];
  const float* bc = (const float*)d_in[8];
  float* out = (float*)d_out;

  // Workspace layout: 2 float buffers + CSR ints.
  float* buf[2];
  buf[0] = (float*)d_ws;
  buf[1] = buf[0] + (size_t)N_NODES * 128;
  int* deg = (int*)(buf[1] + (size_t)N_NODES * 128);  // doubles as cursors
  int* offsets = deg + N_NODES;                        // [N+1]
  int* col = offsets + (N_NODES + 1);                  // [E]

  const dim3 blk(256);
  const int gemm_grid = (N_NODES + 127) / 128;      // 391
  const int edge_grid = (N_EDGES + 255) / 256;      // 2344
  const int aggr_grid = (N_NODES * 32 + 255) / 256; // 6250

  // ---- CSR build (once per call; ws is re-poisoned every timed call) ----
  hipMemsetAsync(deg, 0, N_NODES * sizeof(int), stream);
  count_kernel<<<edge_grid, blk, 0, stream>>>(ei, deg);
  scan_kernel<<<1, 1024, 0, stream>>>(deg, offsets, /*cursors=*/deg);
  fill_kernel<<<edge_grid, blk, 0, stream>>>(ei, /*cursors=*/deg, col);

  // ---- 3 GIN layers ----
  const float* h = x;
  int zi = 0;
  for (int l = 0; l < N_LAYERS; ++l) {
    float* z = buf[zi];
    float* t = buf[1 - zi];
    // z = h + sum_neighbors(h)
    aggregate_kernel<<<aggr_grid, blk, 0, stream>>>(h, offsets, col, z);
    // t = relu(z @ W1[l] + b1[l])
    gemm128_kernel<true><<<gemm_grid, blk, 0, stream>>>(
        z, W1 + (size_t)l * 128 * 128, b1 + (size_t)l * 128, t, N_NODES);
    // z = relu(t @ W2[l] + b2[l])
    gemm128_kernel<true><<<gemm_grid, blk, 0, stream>>>(
        t, W2 + (size_t)l * 128 * 128, b2 + (size_t)l * 128, z, N_NODES);
    h = z;
    zi = 1 - zi;
  }
  // out = h @ Wc + bc
  gemm_out_kernel<<<gemm_grid, blk, 0, stream>>>(h, Wc, bc, out, N_NODES);
}

// Round 4
// 411.780 us; speedup vs baseline: 8.1783x; 1.5682x over previous
//
#include <hip/hip_runtime.h>

#define N_NODES 50000
#define IN_CH 128
#define HID 128
#define OUT_CH 40
#define N_LAYERS 3
#define N_EDGES 600000

typedef __attribute__((ext_vector_type(8))) short short8;
typedef __attribute__((ext_vector_type(4))) float floatx4;

static __device__ __forceinline__ unsigned short f32_to_bf16(float f) {
  unsigned u = __float_as_uint(f);
  unsigned r = 0x7FFFu + ((u >> 16) & 1u);  // RNE
  return (unsigned short)((u + r) >> 16);
}
static __device__ __forceinline__ float bf16_to_f32(unsigned short h) {
  return __uint_as_float(((unsigned)h) << 16);
}

// ===================== prep: x f32 -> bf16 (ushort4/thread) =================
__global__ __launch_bounds__(256) void conv_x_kernel(
    const float* __restrict__ x, unsigned short* __restrict__ xb) {
  int i = (blockIdx.x * 256 + threadIdx.x) * 4;
  if (i >= N_NODES * 128) return;
  float4 v = *(const float4*)(x + i);
  ushort4 o;
  o.x = f32_to_bf16(v.x); o.y = f32_to_bf16(v.y);
  o.z = f32_to_bf16(v.z); o.w = f32_to_bf16(v.w);
  *(ushort4*)(xb + i) = o;
}

// ============ prep: W1,W2 (6 mats 128x128) -> WT bf16 [mat][n][k] ===========
__global__ __launch_bounds__(256) void prep_w_kernel(
    const float* __restrict__ W1, const float* __restrict__ W2,
    unsigned short* __restrict__ WT) {
  int o = blockIdx.x * 256 + threadIdx.x;  // 6*16384
  if (o >= 6 * 16384) return;
  int mat = o >> 14;
  int r = o & 16383;
  int n = r >> 7;
  int k = r & 127;
  // mats 0..2 = W1[l], 3..5 = W2[l]
  const float* W = (mat < 3) ? (W1 + (size_t)mat * 16384)
                             : (W2 + (size_t)(mat - 3) * 16384);
  WT[(size_t)mat * 16384 + (size_t)n * 128 + k] = f32_to_bf16(W[(size_t)k * 128 + n]);
}

// ============================ CSR construction =============================
__global__ __launch_bounds__(256) void count_kernel(
    const int* __restrict__ ei, int* __restrict__ deg) {
  int e = blockIdx.x * 256 + threadIdx.x;
  if (e >= N_EDGES) return;
  atomicAdd(&deg[ei[N_EDGES + e]], 1);
}

// Hierarchical scan: 49 blocks x 1024 elems (256 thr x int4).
__global__ __launch_bounds__(256) void scan1_kernel(
    const int* __restrict__ deg, int* __restrict__ offsets,
    int* __restrict__ btot) {
  __shared__ int s[256];
  const int t = threadIdx.x;
  const int base = blockIdx.x * 1024 + t * 4;
  int4 v = make_int4(0, 0, 0, 0);
  if (base + 3 < N_NODES) {
    v = *(const int4*)(deg + base);
  } else {
    if (base + 0 < N_NODES) v.x = deg[base + 0];
    if (base + 1 < N_NODES) v.y = deg[base + 1];
    if (base + 2 < N_NODES) v.z = deg[base + 2];
    if (base + 3 < N_NODES) v.w = deg[base + 3];
  }
  s[t] = v.x + v.y + v.z + v.w;
  __syncthreads();
  for (int off = 1; off < 256; off <<= 1) {
    int u = (t >= off) ? s[t - off] : 0;
    __syncthreads();
    if (t >= off) s[t] += u;
    __syncthreads();
  }
  int e0 = (t == 0) ? 0 : s[t - 1];
  int4 o;
  o.x = e0;
  o.y = o.x + v.x;
  o.z = o.y + v.y;
  o.w = o.z + v.z;
  if (base + 3 < N_NODES) {
    *(int4*)(offsets + base) = o;
  } else {
    if (base + 0 < N_NODES) offsets[base + 0] = o.x;
    if (base + 1 < N_NODES) offsets[base + 1] = o.y;
    if (base + 2 < N_NODES) offsets[base + 2] = o.z;
    if (base + 3 < N_NODES) offsets[base + 3] = o.w;
  }
  if (t == 255) btot[blockIdx.x] = s[255];
}

#define SCAN_NB 49  // ceil(50000/1024)
__global__ __launch_bounds__(64) void scan2_kernel(
    int* __restrict__ btot, int* __restrict__ offsets) {
  __shared__ int s[64];
  const int t = threadIdx.x;
  s[t] = (t < SCAN_NB) ? btot[t] : 0;
  __syncthreads();
  for (int off = 1; off < 64; off <<= 1) {
    int u = (t >= off) ? s[t - off] : 0;
    __syncthreads();
    if (t >= off) s[t] += u;
    __syncthreads();
  }
  if (t < SCAN_NB) btot[t] = (t == 0) ? 0 : s[t - 1];
  if (t == 63) offsets[N_NODES] = s[63];  // = N_EDGES
}

__global__ __launch_bounds__(256) void scan3_kernel(
    int* __restrict__ offsets, const int* __restrict__ btot,
    int* __restrict__ cursors) {
  const int t = threadIdx.x;
  const int base = blockIdx.x * 1024 + t * 4;
  const int add = btot[blockIdx.x];
  if (base + 3 < N_NODES) {
    int4 v = *(const int4*)(offsets + base);
    v.x += add; v.y += add; v.z += add; v.w += add;
    *(int4*)(offsets + base) = v;
    *(int4*)(cursors + base) = v;
  } else {
    for (int i = 0; i < 4; ++i)
      if (base + i < N_NODES) {
        int v = offsets[base + i] + add;
        offsets[base + i] = v;
        cursors[base + i] = v;
      }
  }
}

__global__ __launch_bounds__(256) void fill_kernel(
    const int* __restrict__ ei, int* __restrict__ cursors,
    int* __restrict__ col) {
  int e = blockIdx.x * 256 + threadIdx.x;
  if (e >= N_EDGES) return;
  int s = ei[e];
  int d = ei[N_EDGES + e];
  int pos = atomicAdd(&cursors[d], 1);
  col[pos] = s;
}

// ================= Aggregation (bf16): z = h[n] + sum_nbrs ==================
// 32 lanes/node, 4 channels/lane (ushort4 = 8B), f32 accumulate.
__global__ __launch_bounds__(256) void aggregate_kernel(
    const unsigned short* __restrict__ h, const int* __restrict__ offsets,
    const int* __restrict__ col, unsigned short* __restrict__ z) {
  int t = blockIdx.x * 256 + threadIdx.x;
  int n = t >> 5;
  int q = t & 31;
  if (n >= N_NODES) return;
  ushort4 sv = *(const ushort4*)(h + (size_t)n * 128 + q * 4);
  float a0 = bf16_to_f32(sv.x), a1 = bf16_to_f32(sv.y);
  float a2 = bf16_to_f32(sv.z), a3 = bf16_to_f32(sv.w);
  int beg = offsets[n], end = offsets[n + 1];
  for (int i = beg; i < end; ++i) {
    int s = col[i];
    ushort4 v = *(const ushort4*)(h + (size_t)s * 128 + q * 4);
    a0 += bf16_to_f32(v.x);
    a1 += bf16_to_f32(v.y);
    a2 += bf16_to_f32(v.z);
    a3 += bf16_to_f32(v.w);
  }
  ushort4 o;
  o.x = f32_to_bf16(a0); o.y = f32_to_bf16(a1);
  o.z = f32_to_bf16(a2); o.w = f32_to_bf16(a3);
  *(ushort4*)(z + (size_t)n * 128 + q * 4) = o;
}

// ================= MFMA GEMM: C = relu(A @ W + b), bf16 ====================
// A[M,128] bf16, WT[n][k] bf16 (pre-transposed), C[M,128] bf16.
// 64-row tile/block, 256 thr = 4 waves; wave w: rows w*16..+15, all 8 col
// tiles. mfma_f32_16x16x32_bf16; A/B frag [idx=lane&15][k=(lane>>4)*8+j],
// C/D row=(lane>>4)*4+reg, col=lane&15 (measured m89/m91).
// LDS pitch 136 elems (272B): quad lanes land 4 banks apart -> <=2-way.
__global__ __launch_bounds__(256) void gemm_mfma_kernel(
    const unsigned short* __restrict__ A, const unsigned short* __restrict__ WT,
    const float* __restrict__ bias, unsigned short* __restrict__ C, int M) {
  __shared__ __align__(16) unsigned short As[64][136];
  __shared__ __align__(16) unsigned short Ws[128][136];
  const int tid = threadIdx.x;
  const int row0 = blockIdx.x * 64;
  const int w = tid >> 6;
  const int lane = tid & 63;
  const int qg = lane >> 4;   // k-group
  const int ln = lane & 15;   // m/n within tile

  // Stage A: 64 rows x 16 chunks(8 bf16).
#pragma unroll
  for (int j = 0; j < 4; ++j) {
    int c = tid + j * 256;  // 0..1023
    int row = c >> 4;
    int kb = c & 15;
    int gm = row0 + row;
    short8 v = {0, 0, 0, 0, 0, 0, 0, 0};
    if (gm < M) v = *(const short8*)(A + (size_t)gm * 128 + kb * 8);
    *(short8*)&As[row][kb * 8] = v;
  }
  // Stage WT: 128 rows x 16 chunks.
#pragma unroll
  for (int j = 0; j < 8; ++j) {
    int c = tid + j * 256;  // 0..2047
    int row = c >> 4;
    int kb = c & 15;
    short8 v = *(const short8*)(WT + (size_t)row * 128 + kb * 8);
    *(short8*)&Ws[row][kb * 8] = v;
  }
  __syncthreads();

  floatx4 acc[8];
#pragma unroll
  for (int ct = 0; ct < 8; ++ct) acc[ct] = (floatx4){0.f, 0.f, 0.f, 0.f};

#pragma unroll
  for (int ks = 0; ks < 4; ++ks) {
    short8 af = *(const short8*)&As[w * 16 + ln][ks * 32 + qg * 8];
    short8 bf[8];
#pragma unroll
    for (int ct = 0; ct < 8; ++ct)
      bf[ct] = *(const short8*)&Ws[ct * 16 + ln][ks * 32 + qg * 8];
#pragma unroll
    for (int ct = 0; ct < 8; ++ct)
      acc[ct] = __builtin_amdgcn_mfma_f32_16x16x32_bf16(af, bf[ct], acc[ct], 0, 0, 0);
  }

  // Epilogue: bias + relu + bf16 store. row = row0+w*16+qg*4+r, col = ct*16+ln.
#pragma unroll
  for (int ct = 0; ct < 8; ++ct) {
    int colg = ct * 16 + ln;
    float bv = bias[colg];
#pragma unroll
    for (int r = 0; r < 4; ++r) {
      int row = row0 + w * 16 + qg * 4 + r;
      if (row < M) {
        float v = acc[ct][r] + bv;
        v = fmaxf(v, 0.0f);
        C[(size_t)row * 128 + colg] = f32_to_bf16(v);
      }
    }
  }
}

// ============== Final classifier: out[M,40] f32 = A(bf16) @ Wc + bc =========
__global__ __launch_bounds__(256) void gemm_out_kernel(
    const unsigned short* __restrict__ A, const float* __restrict__ W,
    const float* __restrict__ bias, float* __restrict__ C, int M) {
  __shared__ float As[32][132];
  __shared__ float Ws[32][48];
  const int tid = threadIdx.x;
  const int row0 = blockIdx.x * 128;
  const int tx = tid & 7;   // cols tx*5..+4
  const int ty = tid >> 3;  // rows ty*4..+3

  float acc[4][5];
#pragma unroll
  for (int r = 0; r < 4; ++r)
#pragma unroll
    for (int c = 0; c < 5; ++c) acc[r][c] = 0.0f;

  for (int k0 = 0; k0 < 128; k0 += 32) {
#pragma unroll
    for (int j = 0; j < 2; ++j) {
      int c = tid + j * 256;  // 0..511
      int m = c >> 2;
      int kq = c & 3;  // 8-elem chunk
      int gm = row0 + m;
      short8 u = {0, 0, 0, 0, 0, 0, 0, 0};
      if (gm < M) u = *(const short8*)(A + (size_t)gm * 128 + k0 + kq * 8);
#pragma unroll
      for (int i = 0; i < 8; ++i)
        As[kq * 8 + i][m] = bf16_to_f32((unsigned short)u[i]);
    }
    for (int i = tid; i < 32 * 40; i += 256) {
      int k = i / 40;
      int n = i % 40;
      Ws[k][n] = W[(size_t)(k0 + k) * 40 + n];
    }
    __syncthreads();

#pragma unroll
    for (int k = 0; k < 32; ++k) {
      float4 a = *(const float4*)&As[k][ty * 4];
      float ar[4] = {a.x, a.y, a.z, a.w};
      float wr[5];
#pragma unroll
      for (int c = 0; c < 5; ++c) wr[c] = Ws[k][tx * 5 + c];
#pragma unroll
      for (int r = 0; r < 4; ++r)
#pragma unroll
        for (int c = 0; c < 5; ++c) acc[r][c] = fmaf(ar[r], wr[c], acc[r][c]);
    }
    __syncthreads();
  }

#pragma unroll
  for (int r = 0; r < 4; ++r) {
    int gm = row0 + ty * 4 + r;
    if (gm < M) {
#pragma unroll
      for (int c = 0; c < 5; ++c)
        C[(size_t)gm * OUT_CH + tx * 5 + c] = acc[r][c] + bias[tx * 5 + c];
    }
  }
}

// ---------------------------------------------------------------------------
extern "C" void kernel_launch(void* const* d_in, const int* in_sizes, int n_in,
                              void* d_out, int out_size, void* d_ws,
                              size_t ws_size, hipStream_t stream) {
  const float* x = (const float*)d_in[0];
  const int* ei = (const int*)d_in[2];  // int32 [2, E]
  const float* W1 = (const float*)d_in[3];
  const float* b1 = (const float*)d_in[4];
  const float* W2 = (const float*)d_in[5];
  const float* b2 = (const float*)d_in[6];
  const float* Wc = (const float*)d_in[7];
  const float* bc = (const float*)d_in[8];
  float* out = (float*)d_out;

  // ws layout: hb0, hb1, xbf (bf16 node bufs), WT (bf16), ints.
  const size_t NF = (size_t)N_NODES * 128;
  unsigned short* hb0 = (unsigned short*)d_ws;
  unsigned short* hb1 = hb0 + NF;
  unsigned short* xbf = hb1 + NF;
  unsigned short* WT = xbf + NF;            // 6*16384
  int* deg = (int*)(WT + 6 * 16384);        // [N] (reused as cursors)
  int* btot = deg + N_NODES;                // [64]
  int* offsets = btot + 64;                 // [N+1]
  int* col = offsets + (N_NODES + 1);       // [E]

  const dim3 blk(256);
  const int edge_grid = (N_EDGES + 255) / 256;       // 2344
  const int aggr_grid = (N_NODES * 32 + 255) / 256;  // 6250
  const int mfma_grid = (N_NODES + 63) / 64;         // 782
  const int out_grid = (N_NODES + 127) / 128;        // 391

  // ---- prep (bf16 conversions) ----
  conv_x_kernel<<<(N_NODES * 128 / 4 + 255) / 256, blk, 0, stream>>>(x, xbf);
  prep_w_kernel<<<(6 * 16384 + 255) / 256, blk, 0, stream>>>(W1, W2, WT);

  // ---- CSR build ----
  hipMemsetAsync(deg, 0, N_NODES * sizeof(int), stream);
  count_kernel<<<edge_grid, blk, 0, stream>>>(ei, deg);
  scan1_kernel<<<SCAN_NB, blk, 0, stream>>>(deg, offsets, btot);
  scan2_kernel<<<1, 64, 0, stream>>>(btot, offsets);
  scan3_kernel<<<SCAN_NB, blk, 0, stream>>>(offsets, btot, /*cursors=*/deg);
  fill_kernel<<<edge_grid, blk, 0, stream>>>(ei, /*cursors=*/deg, col);

  // ---- 3 GIN layers (bf16 activations) ----
  const unsigned short* h = xbf;
  for (int l = 0; l < N_LAYERS; ++l) {
    unsigned short* z = (h == hb0) ? hb1 : hb0;
    unsigned short* o = (z == hb0) ? hb1 : hb0;
    aggregate_kernel<<<aggr_grid, blk, 0, stream>>>(h, offsets, col, z);
    gemm_mfma_kernel<<<mfma_grid, blk, 0, stream>>>(
        z, WT + (size_t)l * 16384, b1 + (size_t)l * 128, o, N_NODES);
    gemm_mfma_kernel<<<mfma_grid, blk, 0, stream>>>(
        o, WT + (size_t)(3 + l) * 16384, b2 + (size_t)l * 128, z, N_NODES);
    h = z;
  }
  // out = h @ Wc + bc (f32 out)
  gemm_out_kernel<<<out_grid, blk, 0, stream>>>(h, Wc, bc, out, N_NODES);
}

// Round 6
// 328.929 us; speedup vs baseline: 10.2383x; 1.2519x over previous
//
#include <hip/hip_runtime.h>

#define N_NODES 50000
#define IN_CH 128
#define HID 128
#define OUT_CH 40
#define N_LAYERS 3
#define N_EDGES 600000

typedef __attribute__((ext_vector_type(8))) short short8;
typedef __attribute__((ext_vector_type(4))) float floatx4;

static __device__ __forceinline__ unsigned short f32_to_bf16(float f) {
  unsigned u = __float_as_uint(f);
  unsigned r = 0x7FFFu + ((u >> 16) & 1u);  // RNE
  return (unsigned short)((u + r) >> 16);
}
static __device__ __forceinline__ float bf16_to_f32(unsigned short h) {
  return __uint_as_float(((unsigned)h) << 16);
}

// ===================== prep: x f32 -> bf16 (ushort4/thread) =================
__global__ __launch_bounds__(256) void conv_x_kernel(
    const float* __restrict__ x, unsigned short* __restrict__ xb) {
  int i = (blockIdx.x * 256 + threadIdx.x) * 4;
  if (i >= N_NODES * 128) return;
  float4 v = *(const float4*)(x + i);
  ushort4 o;
  o.x = f32_to_bf16(v.x); o.y = f32_to_bf16(v.y);
  o.z = f32_to_bf16(v.z); o.w = f32_to_bf16(v.w);
  *(ushort4*)(xb + i) = o;
}

// ============ prep: W1,W2 (6 mats 128x128) -> WT bf16 [mat][n][k] ===========
__global__ __launch_bounds__(256) void prep_w_kernel(
    const float* __restrict__ W1, const float* __restrict__ W2,
    unsigned short* __restrict__ WT) {
  int o = blockIdx.x * 256 + threadIdx.x;
  if (o >= 6 * 16384) return;
  int mat = o >> 14;
  int r = o & 16383;
  int n = r >> 7;
  int k = r & 127;
  const float* W = (mat < 3) ? (W1 + (size_t)mat * 16384)
                             : (W2 + (size_t)(mat - 3) * 16384);
  WT[(size_t)mat * 16384 + (size_t)n * 128 + k] = f32_to_bf16(W[(size_t)k * 128 + n]);
}

// ============================ CSR construction =============================
__global__ __launch_bounds__(256) void count_kernel(
    const int* __restrict__ ei, int* __restrict__ deg) {
  int e = blockIdx.x * 256 + threadIdx.x;
  if (e >= N_EDGES) return;
  atomicAdd(&deg[ei[N_EDGES + e]], 1);
}

__global__ __launch_bounds__(256) void scan1_kernel(
    const int* __restrict__ deg, int* __restrict__ offsets,
    int* __restrict__ btot) {
  __shared__ int s[256];
  const int t = threadIdx.x;
  const int base = blockIdx.x * 1024 + t * 4;
  int4 v = make_int4(0, 0, 0, 0);
  if (base + 3 < N_NODES) {
    v = *(const int4*)(deg + base);
  } else {
    if (base + 0 < N_NODES) v.x = deg[base + 0];
    if (base + 1 < N_NODES) v.y = deg[base + 1];
    if (base + 2 < N_NODES) v.z = deg[base + 2];
    if (base + 3 < N_NODES) v.w = deg[base + 3];
  }
  s[t] = v.x + v.y + v.z + v.w;
  __syncthreads();
  for (int off = 1; off < 256; off <<= 1) {
    int u = (t >= off) ? s[t - off] : 0;
    __syncthreads();
    if (t >= off) s[t] += u;
    __syncthreads();
  }
  int e0 = (t == 0) ? 0 : s[t - 1];
  int4 o;
  o.x = e0; o.y = o.x + v.x; o.z = o.y + v.y; o.w = o.z + v.z;
  if (base + 3 < N_NODES) {
    *(int4*)(offsets + base) = o;
  } else {
    if (base + 0 < N_NODES) offsets[base + 0] = o.x;
    if (base + 1 < N_NODES) offsets[base + 1] = o.y;
    if (base + 2 < N_NODES) offsets[base + 2] = o.z;
    if (base + 3 < N_NODES) offsets[base + 3] = o.w;
  }
  if (t == 255) btot[blockIdx.x] = s[255];
}

#define SCAN_NB 49  // ceil(50000/1024)
__global__ __launch_bounds__(64) void scan2_kernel(
    int* __restrict__ btot, int* __restrict__ offsets) {
  __shared__ int s[64];
  const int t = threadIdx.x;
  s[t] = (t < SCAN_NB) ? btot[t] : 0;
  __syncthreads();
  for (int off = 1; off < 64; off <<= 1) {
    int u = (t >= off) ? s[t - off] : 0;
    __syncthreads();
    if (t >= off) s[t] += u;
    __syncthreads();
  }
  if (t < SCAN_NB) btot[t] = (t == 0) ? 0 : s[t - 1];
  if (t == 63) offsets[N_NODES] = s[63];
}

__global__ __launch_bounds__(256) void scan3_kernel(
    int* __restrict__ offsets, const int* __restrict__ btot,
    int* __restrict__ cursors) {
  const int t = threadIdx.x;
  const int base = blockIdx.x * 1024 + t * 4;
  const int add = btot[blockIdx.x];
  if (base + 3 < N_NODES) {
    int4 v = *(const int4*)(offsets + base);
    v.x += add; v.y += add; v.z += add; v.w += add;
    *(int4*)(offsets + base) = v;
    *(int4*)(cursors + base) = v;
  } else {
    for (int i = 0; i < 4; ++i)
      if (base + i < N_NODES) {
        int v = offsets[base + i] + add;
        offsets[base + i] = v;
        cursors[base + i] = v;
      }
  }
}

__global__ __launch_bounds__(256) void fill_kernel(
    const int* __restrict__ ei, int* __restrict__ cursors,
    int* __restrict__ col) {
  int e = blockIdx.x * 256 + threadIdx.x;
  if (e >= N_EDGES) return;
  int s = ei[e];
  int d = ei[N_EDGES + e];
  int pos = atomicAdd(&cursors[d], 1);
  col[pos] = s;
}

// ================= Aggregation (bf16): z = h[n] + sum_nbrs ==================
// One 64-lane wave per node; lane owns 2 channels (ushort2 = 4B; 64*4B = one
// full 256B row per wave-gather). Node id / offsets / col indices are
// wave-uniform via readfirstlane -> scalar loads. 4-edge unroll for MLP.
__global__ __launch_bounds__(256) void aggregate_kernel(
    const unsigned short* __restrict__ h, const int* __restrict__ offsets,
    const int* __restrict__ col, unsigned short* __restrict__ z) {
  int n = __builtin_amdgcn_readfirstlane(blockIdx.x * 4 + (threadIdx.x >> 6));
  int q = threadIdx.x & 63;
  const size_t co = (size_t)q * 2;
  ushort2 sv = *(const ushort2*)(h + (size_t)n * 128 + co);
  float a0 = bf16_to_f32(sv.x), a1 = bf16_to_f32(sv.y);
  float b0 = 0.f, b1 = 0.f;
  int beg = __builtin_amdgcn_readfirstlane(offsets[n]);
  int end = __builtin_amdgcn_readfirstlane(offsets[n + 1]);
  int i = beg;
  for (; i + 3 < end; i += 4) {
    int s0 = __builtin_amdgcn_readfirstlane(col[i + 0]);
    int s1 = __builtin_amdgcn_readfirstlane(col[i + 1]);
    int s2 = __builtin_amdgcn_readfirstlane(col[i + 2]);
    int s3 = __builtin_amdgcn_readfirstlane(col[i + 3]);
    ushort2 v0 = *(const ushort2*)(h + (size_t)s0 * 128 + co);
    ushort2 v1 = *(const ushort2*)(h + (size_t)s1 * 128 + co);
    ushort2 v2 = *(const ushort2*)(h + (size_t)s2 * 128 + co);
    ushort2 v3 = *(const ushort2*)(h + (size_t)s3 * 128 + co);
    a0 += bf16_to_f32(v0.x); a1 += bf16_to_f32(v0.y);
    b0 += bf16_to_f32(v1.x); b1 += bf16_to_f32(v1.y);
    a0 += bf16_to_f32(v2.x); a1 += bf16_to_f32(v2.y);
    b0 += bf16_to_f32(v3.x); b1 += bf16_to_f32(v3.y);
  }
  for (; i < end; ++i) {
    int s = __builtin_amdgcn_readfirstlane(col[i]);
    ushort2 v = *(const ushort2*)(h + (size_t)s * 128 + co);
    a0 += bf16_to_f32(v.x); a1 += bf16_to_f32(v.y);
  }
  a0 += b0; a1 += b1;
  ushort2 o;
  o.x = f32_to_bf16(a0); o.y = f32_to_bf16(a1);
  *(ushort2*)(z + (size_t)n * 128 + co) = o;
}

// ============ Fused layer MLP: Z = relu(relu(A@W1+b1)@W2+b2) ===============
// 128 rows/block, 4 waves; wave w owns rows w*32..+31 (2 m-tiles of 16).
// Operand fragments loaded DIRECTLY from global (A rows fully consumed by the
// 4 k-groups; WT 32KB is L1-hot). Intermediate t round-trips through a
// per-wave-private LDS region in A-fragment layout (no barrier needed; LDS
// ops within a wave are ordered). Single __syncthreads before the final
// cooperative coalesced store.
// Frag layouts (measured m89/m91): A/B [idx=lane&15][k=(lane>>4)*8+j];
// C/D row=(lane>>4)*4+reg, col=lane&15.
__global__ __launch_bounds__(256) void layer_pair_kernel(
    const unsigned short* __restrict__ A, const unsigned short* __restrict__ WT1,
    const float* __restrict__ b1, const unsigned short* __restrict__ WT2,
    const float* __restrict__ b2, unsigned short* __restrict__ Z, int M) {
  __shared__ __align__(16) unsigned short T[128][136];  // pitch 272B: 2-way max
  const int tid = threadIdx.x;
  const int w = tid >> 6;
  const int lane = tid & 63;
  const int qg = lane >> 4;
  const int ln = lane & 15;
  const int row0 = blockIdx.x * 128;
  const int rbase = w * 32;

  floatx4 acc[2][8];
#pragma unroll
  for (int mt = 0; mt < 2; ++mt)
#pragma unroll
    for (int ct = 0; ct < 8; ++ct) acc[mt][ct] = (floatx4){0.f, 0.f, 0.f, 0.f};

  const int r0 = row0 + rbase + ln;
  const int r1 = r0 + 16;
  const short8 zero8 = {0, 0, 0, 0, 0, 0, 0, 0};

  // ---- GEMM1: direct-global fragments ----
#pragma unroll
  for (int ks = 0; ks < 4; ++ks) {
    const int koff = ks * 32 + qg * 8;
    short8 a0 = (r0 < M) ? *(const short8*)(A + (size_t)r0 * 128 + koff) : zero8;
    short8 a1 = (r1 < M) ? *(const short8*)(A + (size_t)r1 * 128 + koff) : zero8;
#pragma unroll
    for (int ct = 0; ct < 8; ++ct) {
      short8 b = *(const short8*)(WT1 + (size_t)(ct * 16 + ln) * 128 + koff);
      acc[0][ct] = __builtin_amdgcn_mfma_f32_16x16x32_bf16(a0, b, acc[0][ct], 0, 0, 0);
      acc[1][ct] = __builtin_amdgcn_mfma_f32_16x16x32_bf16(a1, b, acc[1][ct], 0, 0, 0);
    }
  }

  // ---- epilogue1 -> LDS (bias+relu+bf16), wave-private rows ----
#pragma unroll
  for (int ct = 0; ct < 8; ++ct) {
    float bv = b1[ct * 16 + ln];
#pragma unroll
    for (int mt = 0; mt < 2; ++mt)
#pragma unroll
      for (int r = 0; r < 4; ++r) {
        float v = fmaxf(acc[mt][ct][r] + bv, 0.0f);
        T[rbase + mt * 16 + qg * 4 + r][ct * 16 + ln] = f32_to_bf16(v);
      }
  }

  // ---- GEMM2: A-fragments from LDS (own rows only), B direct-global ----
  floatx4 acc2[2][8];
#pragma unroll
  for (int mt = 0; mt < 2; ++mt)
#pragma unroll
    for (int ct = 0; ct < 8; ++ct) acc2[mt][ct] = (floatx4){0.f, 0.f, 0.f, 0.f};
#pragma unroll
  for (int ks = 0; ks < 4; ++ks) {
    const int koff = ks * 32 + qg * 8;
    short8 a0 = *(const short8*)&T[rbase + ln][koff];
    short8 a1 = *(const short8*)&T[rbase + 16 + ln][koff];
#pragma unroll
    for (int ct = 0; ct < 8; ++ct) {
      short8 b = *(const short8*)(WT2 + (size_t)(ct * 16 + ln) * 128 + koff);
      acc2[0][ct] = __builtin_amdgcn_mfma_f32_16x16x32_bf16(a0, b, acc2[0][ct], 0, 0, 0);
      acc2[1][ct] = __builtin_amdgcn_mfma_f32_16x16x32_bf16(a1, b, acc2[1][ct], 0, 0, 0);
    }
  }

  // ---- epilogue2 -> LDS (bias+relu+bf16), own rows (just finished reading) --
#pragma unroll
  for (int ct = 0; ct < 8; ++ct) {
    float bv = b2[ct * 16 + ln];
#pragma unroll
    for (int mt = 0; mt < 2; ++mt)
#pragma unroll
      for (int r = 0; r < 4; ++r) {
        float v = fmaxf(acc2[mt][ct][r] + bv, 0.0f);
        T[rbase + mt * 16 + qg * 4 + r][ct * 16 + ln] = f32_to_bf16(v);
      }
  }
  __syncthreads();

  // ---- cooperative coalesced store: 128 rows x 256B ----
#pragma unroll
  for (int j = 0; j < 8; ++j) {
    int slot = tid + j * 256;  // 0..2047 chunks of 8 bf16
    int row = slot >> 4;
    int kb = slot & 15;
    if (row0 + row < M) {
      short8 v = *(const short8*)&T[row][kb * 8];
      *(short8*)(Z + (size_t)(row0 + row) * 128 + kb * 8) = v;
    }
  }
}

// ============== Final classifier: out[M,40] f32 = A(bf16) @ Wc + bc =========
__global__ __launch_bounds__(256) void gemm_out_kernel(
    const unsigned short* __restrict__ A, const float* __restrict__ W,
    const float* __restrict__ bias, float* __restrict__ C, int M) {
  __shared__ float As[32][132];
  __shared__ float Ws[32][48];
  const int tid = threadIdx.x;
  const int row0 = blockIdx.x * 128;
  const int tx = tid & 7;
  const int ty = tid >> 3;

  float acc[4][5];
#pragma unroll
  for (int r = 0; r < 4; ++r)
#pragma unroll
    for (int c = 0; c < 5; ++c) acc[r][c] = 0.0f;

  for (int k0 = 0; k0 < 128; k0 += 32) {
#pragma unroll
    for (int j = 0; j < 2; ++j) {
      int c = tid + j * 256;
      int m = c >> 2;
      int kq = c & 3;
      int gm = row0 + m;
      short8 u = {0, 0, 0, 0, 0, 0, 0, 0};
      if (gm < M) u = *(const short8*)(A + (size_t)gm * 128 + k0 + kq * 8);
#pragma unroll
      for (int i = 0; i < 8; ++i)
        As[kq * 8 + i][m] = bf16_to_f32((unsigned short)u[i]);
    }
    for (int i = tid; i < 32 * 40; i += 256) {
      int k = i / 40;
      int n = i % 40;
      Ws[k][n] = W[(size_t)(k0 + k) * 40 + n];
    }
    __syncthreads();

#pragma unroll
    for (int k = 0; k < 32; ++k) {
      float4 a = *(const float4*)&As[k][ty * 4];
      float ar[4] = {a.x, a.y, a.z, a.w};
      float wr[5];
#pragma unroll
      for (int c = 0; c < 5; ++c) wr[c] = Ws[k][tx * 5 + c];
#pragma unroll
      for (int r = 0; r < 4; ++r)
#pragma unroll
        for (int c = 0; c < 5; ++c) acc[r][c] = fmaf(ar[r], wr[c], acc[r][c]);
    }
    __syncthreads();
  }

#pragma unroll
  for (int r = 0; r < 4; ++r) {
    int gm = row0 + ty * 4 + r;
    if (gm < M) {
#pragma unroll
      for (int c = 0; c < 5; ++c)
        C[(size_t)gm * OUT_CH + tx * 5 + c] = acc[r][c] + bias[tx * 5 + c];
    }
  }
}

// ---------------------------------------------------------------------------
extern "C" void kernel_launch(void* const* d_in, const int* in_sizes, int n_in,
                              void* d_out, int out_size, void* d_ws,
                              size_t ws_size, hipStream_t stream) {
  const float* x = (const float*)d_in[0];
  const int* ei = (const int*)d_in[2];  // int32 [2, E]
  const float* W1 = (const float*)d_in[3];
  const float* b1 = (const float*)d_in[4];
  const float* W2 = (const float*)d_in[5];
  const float* b2 = (const float*)d_in[6];
  const float* Wc = (const float*)d_in[7];
  const float* bc = (const float*)d_in[8];
  float* out = (float*)d_out;

  const size_t NF = (size_t)N_NODES * 128;
  unsigned short* hb0 = (unsigned short*)d_ws;
  unsigned short* hb1 = hb0 + NF;
  unsigned short* xbf = hb1 + NF;
  unsigned short* WT = xbf + NF;       // 6*16384 bf16
  int* deg = (int*)(WT + 6 * 16384);   // [N] (reused as cursors)
  int* btot = deg + N_NODES;           // [64]
  int* offsets = btot + 64;            // [N+1]
  int* col = offsets + (N_NODES + 1);  // [E]

  const dim3 blk(256);
  const int edge_grid = (N_EDGES + 255) / 256;   // 2344
  const int aggr_grid = N_NODES / 4;             // 12500 (divides exactly)
  const int pair_grid = (N_NODES + 127) / 128;   // 391
  const int out_grid = (N_NODES + 127) / 128;    // 391

  // ---- prep ----
  conv_x_kernel<<<(N_NODES * 128 / 4 + 255) / 256, blk, 0, stream>>>(x, xbf);
  prep_w_kernel<<<(6 * 16384 + 255) / 256, blk, 0, stream>>>(W1, W2, WT);

  // ---- CSR build ----
  hipMemsetAsync(deg, 0, N_NODES * sizeof(int), stream);
  count_kernel<<<edge_grid, blk, 0, stream>>>(ei, deg);
  scan1_kernel<<<SCAN_NB, blk, 0, stream>>>(deg, offsets, btot);
  scan2_kernel<<<1, 64, 0, stream>>>(btot, offsets);
  scan3_kernel<<<SCAN_NB, blk, 0, stream>>>(offsets, btot, /*cursors=*/deg);
  fill_kernel<<<edge_grid, blk, 0, stream>>>(ei, /*cursors=*/deg, col);

  // ---- 3 GIN layers ----
  // Fixed buffer assignment (R5 bug: rotation aliased agg src & dst):
  //   agg: h -> hb0 ; pair: hb0 -> hb1 ; next h = hb1.
  // pair may overwrite old h (dead after agg); agg src is never its dst.
  const unsigned short* h = xbf;
  for (int l = 0; l < N_LAYERS; ++l) {
    aggregate_kernel<<<aggr_grid, blk, 0, stream>>>(h, offsets, col, hb0);
    layer_pair_kernel<<<pair_grid, blk, 0, stream>>>(
        hb0, WT + (size_t)l * 16384, b1 + (size_t)l * 128,
        WT + (size_t)(3 + l) * 16384, b2 + (size_t)l * 128, hb1, N_NODES);
    h = hb1;
  }
  // out = h @ Wc + bc (f32)
  gemm_out_kernel<<<out_grid, blk, 0, stream>>>(h, Wc, bc, out, N_NODES);
}